// Round 3
// baseline (387.643 us; speedup 1.0000x reference)
//
#include <hip/hip_runtime.h>
#include <hip/hip_fp16.h>

#define N_NODES 50000
#define N_EDGES 800000
#define EDIM 16
#define NEG_SLOPE 0.2f

// ============================ CSR build ============================
__global__ void count_kernel(const int* __restrict__ ei, int* __restrict__ cnt) {
    int e = blockIdx.x * blockDim.x + threadIdx.x;
    if (e < N_EDGES) atomicAdd(&cnt[ei[N_EDGES + e]], 1);
}

__global__ void scan_block_kernel(const int* __restrict__ in, int* __restrict__ excl,
                                  int* __restrict__ bsums, int n) {
    __shared__ int sh[256];
    int tid = threadIdx.x;
    int gid = blockIdx.x * 256 + tid;
    int v = (gid < n) ? in[gid] : 0;
    sh[tid] = v;
    __syncthreads();
    for (int off = 1; off < 256; off <<= 1) {
        int t = (tid >= off) ? sh[tid - off] : 0;
        __syncthreads();
        sh[tid] += t;
        __syncthreads();
    }
    if (gid < n) excl[gid] = sh[tid] - v;
    if (bsums != nullptr && tid == 255) bsums[blockIdx.x] = sh[tid];
}

__global__ void scan_add_kernel(const int* __restrict__ excl, const int* __restrict__ bs2,
                                int* __restrict__ csr_off, int* __restrict__ cursor,
                                int n, int total) {
    int gid = blockIdx.x * 256 + threadIdx.x;
    if (gid < n) {
        int v = excl[gid] + bs2[gid >> 8];
        csr_off[gid] = v;
        cursor[gid] = v;
    }
    if (gid == 0) csr_off[n] = total;
}

// writes CSR edge id, CSR src node, and edge->CSR-slot map
__global__ void scatter_kernel(const int* __restrict__ ei, int* __restrict__ cursor,
                               int* __restrict__ csr_eid, int* __restrict__ csr_src,
                               int* __restrict__ epos) {
    int e = blockIdx.x * blockDim.x + threadIdx.x;
    if (e < N_EDGES) {
        int s = ei[e];
        int d = ei[N_EDGES + e];
        int pos = atomicAdd(&cursor[d], 1);
        csr_eid[pos] = e;
        csr_src[pos] = s;
        epos[e] = pos;
    }
}

// ============================ shared precompute ============================
// w_e[h*16+d] = sum_c We[d][h*64+c] * ae[h][c]
__global__ void we_kernel(const float* __restrict__ We, const float* __restrict__ ae,
                          float* __restrict__ w_e) {
    int idx = threadIdx.x;
    if (idx >= 32) return;
    int h = idx >> 4, d = idx & 15;
    float s = 0.f;
    for (int c = 0; c < 64; ++c) s += We[d * 128 + h * 64 + c] * ae[h * 64 + c];
    w_e[idx] = s;
}

// per-edge attention-edge dots for BOTH layers: a_e4[k] = {l1h0, l1h1, l2h0, l2h1}
__global__ void edge_dot_kernel(const float* __restrict__ edge_attr,
                                const float* __restrict__ we1, const float* __restrict__ we2,
                                float4* __restrict__ a_e4) {
    int k = blockIdx.x * blockDim.x + threadIdx.x;
    if (k >= N_EDGES) return;
    float4 d = make_float4(0.f, 0.f, 0.f, 0.f);
#pragma unroll
    for (int q = 0; q < 4; ++q) {
        float4 v = *reinterpret_cast<const float4*>(edge_attr + (size_t)k * 16 + q * 4);
        float4 wa = *reinterpret_cast<const float4*>(we1 + q * 4);
        float4 wb = *reinterpret_cast<const float4*>(we1 + 16 + q * 4);
        float4 wc = *reinterpret_cast<const float4*>(we2 + q * 4);
        float4 wd = *reinterpret_cast<const float4*>(we2 + 16 + q * 4);
        d.x += v.x * wa.x + v.y * wa.y + v.z * wa.z + v.w * wa.w;
        d.y += v.x * wb.x + v.y * wb.y + v.z * wb.z + v.w * wb.w;
        d.z += v.x * wc.x + v.y * wc.y + v.z * wc.z + v.w * wc.w;
        d.w += v.x * wd.x + v.y * wd.y + v.z * wd.z + v.w * wd.w;
    }
    a_e4[k] = d;
}

// self-loop edge dot = mean of incoming edges' dots (linearity of dot vs mean attr)
__global__ void self_mean_kernel(const float4* __restrict__ a_e4, const int* __restrict__ csr_off,
                                 const int* __restrict__ csr_eid, float4* __restrict__ ae_self) {
    int n = blockIdx.x * blockDim.x + threadIdx.x;
    if (n >= N_NODES) return;
    int b = csr_off[n], e = csr_off[n + 1];
    float4 s = make_float4(0.f, 0.f, 0.f, 0.f);
    for (int j = b; j < e; ++j) {
        float4 v = a_e4[csr_eid[j]];
        s.x += v.x; s.y += v.y; s.z += v.z; s.w += v.w;
    }
    float inv = 1.f / (float)((e - b) > 0 ? (e - b) : 1);
    s.x *= inv; s.y *= inv; s.z *= inv; s.w *= inv;
    ae_self[n] = s;
}

// ============================ per-layer ============================
// C[M,128] = X[M,K] @ W[K,128]; also writes fp16 copy for the gather kernel
__global__ __launch_bounds__(256) void sgemm_kernel(const float* __restrict__ X,
                                                    const float* __restrict__ W,
                                                    float* __restrict__ Hout,
                                                    __half* __restrict__ H16, int M, int K) {
    __shared__ float xs[128 * 132];
    __shared__ float ws[128 * 132];
    const int tid = threadIdx.x;
    const int row0 = blockIdx.x * 128;
    const int xstride = K + 4;

    for (int q = tid; q < K * 32; q += 256) {
        int k = q >> 5, c4 = q & 31;
        float4 v = *reinterpret_cast<const float4*>(W + k * 128 + c4 * 4);
        *reinterpret_cast<float4*>(&ws[k * 132 + c4 * 4]) = v;
    }
    const int kshift = (K == 128) ? 5 : 4;
    const int kmask = (K >> 2) - 1;
    for (int q = tid; q < (128 << kshift); q += 256) {
        int r = q >> kshift, kq = q & kmask;
        int gr = row0 + r;
        float4 v = make_float4(0.f, 0.f, 0.f, 0.f);
        if (gr < M) v = *reinterpret_cast<const float4*>(X + (size_t)gr * K + kq * 4);
        *reinterpret_cast<float4*>(&xs[r * xstride + kq * 4]) = v;
    }
    __syncthreads();

    const int cg = tid & 15;
    const int rg = (tid >> 4) & 3;
    const int w = tid >> 6;
    const int rbase = w * 32 + rg;

    float acc[8][8];
#pragma unroll
    for (int i = 0; i < 8; ++i)
#pragma unroll
        for (int j = 0; j < 8; ++j) acc[i][j] = 0.f;

    for (int kk = 0; kk < K; kk += 4) {
        float4 a[8], b[8];
#pragma unroll
        for (int i = 0; i < 8; ++i)
            a[i] = *reinterpret_cast<const float4*>(&xs[(rbase + 4 * i) * xstride + kk]);
#pragma unroll
        for (int t = 0; t < 4; ++t) {
            b[t * 2] = *reinterpret_cast<const float4*>(&ws[(kk + t) * 132 + cg * 8]);
            b[t * 2 + 1] = *reinterpret_cast<const float4*>(&ws[(kk + t) * 132 + cg * 8 + 4]);
        }
#pragma unroll
        for (int t = 0; t < 4; ++t) {
            float bv[8];
            bv[0] = b[t * 2].x; bv[1] = b[t * 2].y; bv[2] = b[t * 2].z; bv[3] = b[t * 2].w;
            bv[4] = b[t * 2 + 1].x; bv[5] = b[t * 2 + 1].y; bv[6] = b[t * 2 + 1].z; bv[7] = b[t * 2 + 1].w;
#pragma unroll
            for (int i = 0; i < 8; ++i) {
                float av = (t == 0) ? a[i].x : (t == 1) ? a[i].y : (t == 2) ? a[i].z : a[i].w;
#pragma unroll
                for (int j = 0; j < 8; ++j) acc[i][j] = fmaf(av, bv[j], acc[i][j]);
            }
        }
    }
#pragma unroll
    for (int i = 0; i < 8; ++i) {
        int r = row0 + rbase + 4 * i;
        if (r < M) {
            float4 o0 = {acc[i][0], acc[i][1], acc[i][2], acc[i][3]};
            float4 o1 = {acc[i][4], acc[i][5], acc[i][6], acc[i][7]};
            *reinterpret_cast<float4*>(Hout + (size_t)r * 128 + cg * 8) = o0;
            *reinterpret_cast<float4*>(Hout + (size_t)r * 128 + cg * 8 + 4) = o1;
            __half t16[8];
#pragma unroll
            for (int j = 0; j < 8; ++j) t16[j] = __float2half_rn(acc[i][j]);
            *reinterpret_cast<float4*>(H16 + (size_t)r * 128 + cg * 8) =
                *reinterpret_cast<const float4*>(t16);
        }
    }
}

// a_src[n][h], a_dst[n][h]; one wave per node
__global__ void attdot_kernel(const float* __restrict__ Hb, const float* __restrict__ as,
                              const float* __restrict__ ad, float* __restrict__ a_src,
                              float* __restrict__ a_dst) {
    int wid = (blockIdx.x * blockDim.x + threadIdx.x) >> 6;
    int lane = threadIdx.x & 63;
    if (wid >= N_NODES) return;
    float h0 = Hb[(size_t)wid * 128 + lane];
    float h1 = Hb[(size_t)wid * 128 + 64 + lane];
    float s0 = h0 * as[lane], s1 = h1 * as[64 + lane];
    float d0 = h0 * ad[lane], d1 = h1 * ad[64 + lane];
#pragma unroll
    for (int m = 32; m; m >>= 1) {
        s0 += __shfl_xor(s0, m);
        s1 += __shfl_xor(s1, m);
        d0 += __shfl_xor(d0, m);
        d1 += __shfl_xor(d1, m);
    }
    if (lane == 0) {
        *reinterpret_cast<float2*>(a_src + wid * 2) = make_float2(s0, s1);
        *reinterpret_cast<float2*>(a_dst + wid * 2) = make_float2(d0, d1);
    }
}

// exp(leaky_relu(logit)); edges write into CSR order, self-loops into exl_self
__global__ void edge_logit_kernel(const int* __restrict__ ei,
                                  const float2* __restrict__ ae_pairs,      // a_e4 as float2[2E]
                                  const float2* __restrict__ ae_self_pairs, // ae_self as float2[2N]
                                  int layer,
                                  const float2* __restrict__ a_src, const float2* __restrict__ a_dst,
                                  const int* __restrict__ epos,
                                  float2* __restrict__ exl_csr, float2* __restrict__ exl_self) {
    int k = blockIdx.x * blockDim.x + threadIdx.x;
    if (k >= N_EDGES + N_NODES) return;
    float2 ae, asv, adv;
    if (k < N_EDGES) {
        int s = ei[k], d = ei[N_EDGES + k];
        ae = ae_pairs[2 * (size_t)k + layer];
        asv = a_src[s];
        adv = a_dst[d];
    } else {
        int n = k - N_EDGES;
        ae = ae_self_pairs[2 * (size_t)n + layer];
        asv = a_src[n];
        adv = a_dst[n];
    }
    float al0 = asv.x + adv.x + ae.x;
    float al1 = asv.y + adv.y + ae.y;
    al0 = (al0 > 0.f) ? al0 : NEG_SLOPE * al0;
    al1 = (al1 > 0.f) ? al1 : NEG_SLOPE * al1;
    float2 ex = make_float2(__expf(al0), __expf(al1));  // no max-shift: |alpha| small
    if (k < N_EDGES)
        exl_csr[epos[k]] = ex;
    else
        exl_self[k - N_EDGES] = ex;
}

// one wave per dst node; lane = channel; shfl-broadcast edge data; 3-deep gather pipeline
__global__ void aggregate_kernel(const int* __restrict__ csr_off, const int* __restrict__ csr_src,
                                 const float2* __restrict__ exl_csr,
                                 const float2* __restrict__ exl_self,
                                 const __half* __restrict__ H16, const float* __restrict__ bias,
                                 float* __restrict__ outp, int do_relu) {
    int wid = (blockIdx.x * blockDim.x + threadIdx.x) >> 6;
    int lane = threadIdx.x & 63;
    if (wid >= N_NODES) return;
    int n = wid;
    float2 exs = exl_self[n];
    float den0 = exs.x, den1 = exs.y;
    float acc0 = exs.x * __half2float(H16[(size_t)n * 128 + lane]);
    float acc1 = exs.y * __half2float(H16[(size_t)n * 128 + 64 + lane]);
    int b = csr_off[n], e = csr_off[n + 1];
    for (int base = b; base < e; base += 64) {
        int j = base + lane;
        int sv = 0;
        float2 exv = make_float2(0.f, 0.f);
        if (j < e) { sv = csr_src[j]; exv = exl_csr[j]; }
        int m = e - base;
        if (m > 64) m = 64;
        // 3-deep rotating prefetch (raw half regs; convert at consume)
        int s;
        __half p0a, p0b, p1a, p1b, p2a, p2b;
        s = __shfl(sv, 0);
        p0a = H16[(size_t)s * 128 + lane]; p0b = H16[(size_t)s * 128 + 64 + lane];
        s = __shfl(sv, 1);
        p1a = H16[(size_t)s * 128 + lane]; p1b = H16[(size_t)s * 128 + 64 + lane];
        s = __shfl(sv, 2);
        p2a = H16[(size_t)s * 128 + lane]; p2b = H16[(size_t)s * 128 + 64 + lane];
        for (int t = 0; t < m; ++t) {
            float ex0 = __shfl(exv.x, t);
            float ex1 = __shfl(exv.y, t);
            float g0 = __half2float(p0a);
            float g1 = __half2float(p0b);
            p0a = p1a; p0b = p1b;
            p1a = p2a; p1b = p2b;
            s = __shfl(sv, (t + 3) & 63);
            p2a = H16[(size_t)s * 128 + lane];
            p2b = H16[(size_t)s * 128 + 64 + lane];
            den0 += ex0; den1 += ex1;
            acc0 = fmaf(ex0, g0, acc0);
            acc1 = fmaf(ex1, g1, acc1);
        }
    }
    float r = 0.5f * (acc0 / (den0 + 1e-16f) + acc1 / (den1 + 1e-16f)) + bias[lane];
    if (do_relu) r = fmaxf(r, 0.f);
    outp[(size_t)n * 64 + lane] = r;
}

// ============================ launch ============================
extern "C" void kernel_launch(void* const* d_in, const int* in_sizes, int n_in,
                              void* d_out, int out_size, void* d_ws, size_t ws_size,
                              hipStream_t stream) {
    const float* x = (const float*)d_in[0];
    const int* ei = (const int*)d_in[1];
    const float* edge_attr = (const float*)d_in[2];
    const float* W1 = (const float*)d_in[3];
    const float* We1 = (const float*)d_in[4];
    const float* as1 = (const float*)d_in[5];
    const float* ad1 = (const float*)d_in[6];
    const float* ae1 = (const float*)d_in[7];
    const float* b1 = (const float*)d_in[8];
    const float* W2 = (const float*)d_in[9];
    const float* We2 = (const float*)d_in[10];
    const float* as2 = (const float*)d_in[11];
    const float* ad2 = (const float*)d_in[12];
    const float* ae2 = (const float*)d_in[13];
    const float* b2 = (const float*)d_in[14];
    float* out = (float*)d_out;

    char* ws = (char*)d_ws;
    size_t off = 0;
    auto alloc = [&](size_t bytes) -> void* {
        void* p = ws + off;
        off += (bytes + 255) & ~(size_t)255;
        return p;
    };
    int* cnt = (int*)alloc((size_t)N_NODES * 4);
    int* cursor = (int*)alloc((size_t)N_NODES * 4);
    int* csr_off = (int*)alloc(((size_t)N_NODES + 1) * 4);
    int* csr_eid = (int*)alloc((size_t)N_EDGES * 4);
    int* csr_src = (int*)alloc((size_t)N_EDGES * 4);
    int* epos = (int*)alloc((size_t)N_EDGES * 4);
    int* bsums = (int*)alloc(256 * 4);
    int* bsums2 = (int*)alloc(256 * 4);
    float* hbuf = (float*)alloc((size_t)N_NODES * 128 * 4);
    __half* H16 = (__half*)alloc((size_t)N_NODES * 128 * 2);
    float* h1 = (float*)alloc((size_t)N_NODES * 64 * 4);
    float* a_src = (float*)alloc((size_t)N_NODES * 2 * 4);
    float* a_dst = (float*)alloc((size_t)N_NODES * 2 * 4);
    float2* exl_csr = (float2*)alloc((size_t)N_EDGES * 8);
    float2* exl_self = (float2*)alloc((size_t)N_NODES * 8);
    float4* a_e4 = (float4*)alloc((size_t)N_EDGES * 16);
    float4* ae_self4 = (float4*)alloc((size_t)N_NODES * 16);
    float* w_e1 = (float*)alloc(32 * 4);
    float* w_e2 = (float*)alloc(32 * 4);

    const int nb = (N_NODES + 255) / 256;

    // ---- CSR + shared edge precompute ----
    hipMemsetAsync(cnt, 0, (size_t)N_NODES * 4, stream);
    count_kernel<<<(N_EDGES + 255) / 256, 256, 0, stream>>>(ei, cnt);
    scan_block_kernel<<<nb, 256, 0, stream>>>(cnt, cursor, bsums, N_NODES);
    scan_block_kernel<<<1, 256, 0, stream>>>(bsums, bsums2, nullptr, nb);
    scan_add_kernel<<<nb, 256, 0, stream>>>(cursor, bsums2, csr_off, cursor, N_NODES, N_EDGES);
    scatter_kernel<<<(N_EDGES + 255) / 256, 256, 0, stream>>>(ei, cursor, csr_eid, csr_src, epos);
    we_kernel<<<1, 64, 0, stream>>>(We1, ae1, w_e1);
    we_kernel<<<1, 64, 0, stream>>>(We2, ae2, w_e2);
    edge_dot_kernel<<<(N_EDGES + 255) / 256, 256, 0, stream>>>(edge_attr, w_e1, w_e2, a_e4);
    self_mean_kernel<<<(N_NODES + 255) / 256, 256, 0, stream>>>(a_e4, csr_off, csr_eid, ae_self4);

    const int nodeWaveBlocks = (N_NODES * 64 + 255) / 256;
    const int edgeBlocks = (N_EDGES + N_NODES + 255) / 256;
    const int gemmBlocks = (N_NODES + 127) / 128;

    // ---- layer 1: IN=128 -> HID=64, H=2, relu ----
    sgemm_kernel<<<gemmBlocks, 256, 0, stream>>>(x, W1, hbuf, H16, N_NODES, 128);
    attdot_kernel<<<nodeWaveBlocks, 256, 0, stream>>>(hbuf, as1, ad1, a_src, a_dst);
    edge_logit_kernel<<<edgeBlocks, 256, 0, stream>>>(ei, (const float2*)a_e4, (const float2*)ae_self4, 0,
                                                      (const float2*)a_src, (const float2*)a_dst,
                                                      epos, exl_csr, exl_self);
    aggregate_kernel<<<nodeWaveBlocks, 256, 0, stream>>>(csr_off, csr_src, exl_csr, exl_self, H16, b1, h1, 1);

    // ---- layer 2: HID=64 -> OUT=64, H=2, no relu ----
    sgemm_kernel<<<gemmBlocks, 256, 0, stream>>>(h1, W2, hbuf, H16, N_NODES, 64);
    attdot_kernel<<<nodeWaveBlocks, 256, 0, stream>>>(hbuf, as2, ad2, a_src, a_dst);
    edge_logit_kernel<<<edgeBlocks, 256, 0, stream>>>(ei, (const float2*)a_e4, (const float2*)ae_self4, 1,
                                                      (const float2*)a_src, (const float2*)a_dst,
                                                      epos, exl_csr, exl_self);
    aggregate_kernel<<<nodeWaveBlocks, 256, 0, stream>>>(csr_off, csr_src, exl_csr, exl_self, H16, b2, out, 0);
}

// Round 4
// 383.475 us; speedup vs baseline: 1.0109x; 1.0109x over previous
//
#include <hip/hip_runtime.h>
#include <hip/hip_fp16.h>

#define N_NODES 50000
#define N_EDGES 800000
#define EDIM 16
#define NEG_SLOPE 0.2f

// ============================ CSR build ============================
__global__ void count_kernel(const int* __restrict__ ei, int* __restrict__ cnt) {
    int e = blockIdx.x * blockDim.x + threadIdx.x;
    if (e < N_EDGES) atomicAdd(&cnt[ei[N_EDGES + e]], 1);
}

__global__ void scan_block_kernel(const int* __restrict__ in, int* __restrict__ excl,
                                  int* __restrict__ bsums, int n) {
    __shared__ int sh[256];
    int tid = threadIdx.x;
    int gid = blockIdx.x * 256 + tid;
    int v = (gid < n) ? in[gid] : 0;
    sh[tid] = v;
    __syncthreads();
    for (int off = 1; off < 256; off <<= 1) {
        int t = (tid >= off) ? sh[tid - off] : 0;
        __syncthreads();
        sh[tid] += t;
        __syncthreads();
    }
    if (gid < n) excl[gid] = sh[tid] - v;
    if (bsums != nullptr && tid == 255) bsums[blockIdx.x] = sh[tid];
}

__global__ void scan_add_kernel(const int* __restrict__ excl, const int* __restrict__ bs2,
                                int* __restrict__ csr_off, int* __restrict__ cursor,
                                int n, int total) {
    int gid = blockIdx.x * 256 + threadIdx.x;
    if (gid < n) {
        int v = excl[gid] + bs2[gid >> 8];
        csr_off[gid] = v;
        cursor[gid] = v;
    }
    if (gid == 0) csr_off[n] = total;
}

// writes CSR edge id, CSR src node, and edge->CSR-slot map
__global__ void scatter_kernel(const int* __restrict__ ei, int* __restrict__ cursor,
                               int* __restrict__ csr_eid, int* __restrict__ csr_src,
                               int* __restrict__ epos) {
    int e = blockIdx.x * blockDim.x + threadIdx.x;
    if (e < N_EDGES) {
        int s = ei[e];
        int d = ei[N_EDGES + e];
        int pos = atomicAdd(&cursor[d], 1);
        csr_eid[pos] = e;
        csr_src[pos] = s;
        epos[e] = pos;
    }
}

// ============================ shared precompute ============================
// w_e[h*16+d] = sum_c We[d][h*64+c] * ae[h][c]
__global__ void we_kernel(const float* __restrict__ We, const float* __restrict__ ae,
                          float* __restrict__ w_e) {
    int idx = threadIdx.x;
    if (idx >= 32) return;
    int h = idx >> 4, d = idx & 15;
    float s = 0.f;
    for (int c = 0; c < 64; ++c) s += We[d * 128 + h * 64 + c] * ae[h * 64 + c];
    w_e[idx] = s;
}

// per-edge attention-edge dots for BOTH layers: a_e4[k] = {l1h0, l1h1, l2h0, l2h1}
__global__ void edge_dot_kernel(const float* __restrict__ edge_attr,
                                const float* __restrict__ we1, const float* __restrict__ we2,
                                float4* __restrict__ a_e4) {
    int k = blockIdx.x * blockDim.x + threadIdx.x;
    if (k >= N_EDGES) return;
    float4 d = make_float4(0.f, 0.f, 0.f, 0.f);
#pragma unroll
    for (int q = 0; q < 4; ++q) {
        float4 v = *reinterpret_cast<const float4*>(edge_attr + (size_t)k * 16 + q * 4);
        float4 wa = *reinterpret_cast<const float4*>(we1 + q * 4);
        float4 wb = *reinterpret_cast<const float4*>(we1 + 16 + q * 4);
        float4 wc = *reinterpret_cast<const float4*>(we2 + q * 4);
        float4 wd = *reinterpret_cast<const float4*>(we2 + 16 + q * 4);
        d.x += v.x * wa.x + v.y * wa.y + v.z * wa.z + v.w * wa.w;
        d.y += v.x * wb.x + v.y * wb.y + v.z * wb.z + v.w * wb.w;
        d.z += v.x * wc.x + v.y * wc.y + v.z * wc.z + v.w * wc.w;
        d.w += v.x * wd.x + v.y * wd.y + v.z * wd.z + v.w * wd.w;
    }
    a_e4[k] = d;
}

// self-loop edge dot = mean of incoming edges' dots (linearity of dot vs mean attr)
__global__ void self_mean_kernel(const float4* __restrict__ a_e4, const int* __restrict__ csr_off,
                                 const int* __restrict__ csr_eid, float4* __restrict__ ae_self) {
    int n = blockIdx.x * blockDim.x + threadIdx.x;
    if (n >= N_NODES) return;
    int b = csr_off[n], e = csr_off[n + 1];
    float4 s = make_float4(0.f, 0.f, 0.f, 0.f);
    for (int j = b; j < e; ++j) {
        float4 v = a_e4[csr_eid[j]];
        s.x += v.x; s.y += v.y; s.z += v.z; s.w += v.w;
    }
    float inv = 1.f / (float)((e - b) > 0 ? (e - b) : 1);
    s.x *= inv; s.y *= inv; s.z *= inv; s.w *= inv;
    ae_self[n] = s;
}

// ============================ per-layer ============================
// C[M,128] = X[M,K] @ W[K,128]; also writes fp16 copy for the gather kernel
__global__ __launch_bounds__(256) void sgemm_kernel(const float* __restrict__ X,
                                                    const float* __restrict__ W,
                                                    float* __restrict__ Hout,
                                                    __half* __restrict__ H16, int M, int K) {
    __shared__ float xs[128 * 132];
    __shared__ float ws[128 * 132];
    const int tid = threadIdx.x;
    const int row0 = blockIdx.x * 128;
    const int xstride = K + 4;

    for (int q = tid; q < K * 32; q += 256) {
        int k = q >> 5, c4 = q & 31;
        float4 v = *reinterpret_cast<const float4*>(W + k * 128 + c4 * 4);
        *reinterpret_cast<float4*>(&ws[k * 132 + c4 * 4]) = v;
    }
    const int kshift = (K == 128) ? 5 : 4;
    const int kmask = (K >> 2) - 1;
    for (int q = tid; q < (128 << kshift); q += 256) {
        int r = q >> kshift, kq = q & kmask;
        int gr = row0 + r;
        float4 v = make_float4(0.f, 0.f, 0.f, 0.f);
        if (gr < M) v = *reinterpret_cast<const float4*>(X + (size_t)gr * K + kq * 4);
        *reinterpret_cast<float4*>(&xs[r * xstride + kq * 4]) = v;
    }
    __syncthreads();

    const int cg = tid & 15;
    const int rg = (tid >> 4) & 3;
    const int w = tid >> 6;
    const int rbase = w * 32 + rg;

    float acc[8][8];
#pragma unroll
    for (int i = 0; i < 8; ++i)
#pragma unroll
        for (int j = 0; j < 8; ++j) acc[i][j] = 0.f;

    for (int kk = 0; kk < K; kk += 4) {
        float4 a[8], b[8];
#pragma unroll
        for (int i = 0; i < 8; ++i)
            a[i] = *reinterpret_cast<const float4*>(&xs[(rbase + 4 * i) * xstride + kk]);
#pragma unroll
        for (int t = 0; t < 4; ++t) {
            b[t * 2] = *reinterpret_cast<const float4*>(&ws[(kk + t) * 132 + cg * 8]);
            b[t * 2 + 1] = *reinterpret_cast<const float4*>(&ws[(kk + t) * 132 + cg * 8 + 4]);
        }
#pragma unroll
        for (int t = 0; t < 4; ++t) {
            float bv[8];
            bv[0] = b[t * 2].x; bv[1] = b[t * 2].y; bv[2] = b[t * 2].z; bv[3] = b[t * 2].w;
            bv[4] = b[t * 2 + 1].x; bv[5] = b[t * 2 + 1].y; bv[6] = b[t * 2 + 1].z; bv[7] = b[t * 2 + 1].w;
#pragma unroll
            for (int i = 0; i < 8; ++i) {
                float av = (t == 0) ? a[i].x : (t == 1) ? a[i].y : (t == 2) ? a[i].z : a[i].w;
#pragma unroll
                for (int j = 0; j < 8; ++j) acc[i][j] = fmaf(av, bv[j], acc[i][j]);
            }
        }
    }
#pragma unroll
    for (int i = 0; i < 8; ++i) {
        int r = row0 + rbase + 4 * i;
        if (r < M) {
            float4 o0 = {acc[i][0], acc[i][1], acc[i][2], acc[i][3]};
            float4 o1 = {acc[i][4], acc[i][5], acc[i][6], acc[i][7]};
            *reinterpret_cast<float4*>(Hout + (size_t)r * 128 + cg * 8) = o0;
            *reinterpret_cast<float4*>(Hout + (size_t)r * 128 + cg * 8 + 4) = o1;
            __half t16[8];
#pragma unroll
            for (int j = 0; j < 8; ++j) t16[j] = __float2half_rn(acc[i][j]);
            *reinterpret_cast<float4*>(H16 + (size_t)r * 128 + cg * 8) =
                *reinterpret_cast<const float4*>(t16);
        }
    }
}

// a_src[n][h], a_dst[n][h]; one wave per node
__global__ void attdot_kernel(const float* __restrict__ Hb, const float* __restrict__ as,
                              const float* __restrict__ ad, float* __restrict__ a_src,
                              float* __restrict__ a_dst) {
    int wid = (blockIdx.x * blockDim.x + threadIdx.x) >> 6;
    int lane = threadIdx.x & 63;
    if (wid >= N_NODES) return;
    float h0 = Hb[(size_t)wid * 128 + lane];
    float h1 = Hb[(size_t)wid * 128 + 64 + lane];
    float s0 = h0 * as[lane], s1 = h1 * as[64 + lane];
    float d0 = h0 * ad[lane], d1 = h1 * ad[64 + lane];
#pragma unroll
    for (int m = 32; m; m >>= 1) {
        s0 += __shfl_xor(s0, m);
        s1 += __shfl_xor(s1, m);
        d0 += __shfl_xor(d0, m);
        d1 += __shfl_xor(d1, m);
    }
    if (lane == 0) {
        *reinterpret_cast<float2*>(a_src + wid * 2) = make_float2(s0, s1);
        *reinterpret_cast<float2*>(a_dst + wid * 2) = make_float2(d0, d1);
    }
}

// exp(leaky_relu(logit)); edges write into CSR order, self-loops into exl_self
__global__ void edge_logit_kernel(const int* __restrict__ ei,
                                  const float2* __restrict__ ae_pairs,      // a_e4 as float2[2E]
                                  const float2* __restrict__ ae_self_pairs, // ae_self as float2[2N]
                                  int layer,
                                  const float2* __restrict__ a_src, const float2* __restrict__ a_dst,
                                  const int* __restrict__ epos,
                                  float2* __restrict__ exl_csr, float2* __restrict__ exl_self) {
    int k = blockIdx.x * blockDim.x + threadIdx.x;
    if (k >= N_EDGES + N_NODES) return;
    float2 ae, asv, adv;
    if (k < N_EDGES) {
        int s = ei[k], d = ei[N_EDGES + k];
        ae = ae_pairs[2 * (size_t)k + layer];
        asv = a_src[s];
        adv = a_dst[d];
    } else {
        int n = k - N_EDGES;
        ae = ae_self_pairs[2 * (size_t)n + layer];
        asv = a_src[n];
        adv = a_dst[n];
    }
    float al0 = asv.x + adv.x + ae.x;
    float al1 = asv.y + adv.y + ae.y;
    al0 = (al0 > 0.f) ? al0 : NEG_SLOPE * al0;
    al1 = (al1 > 0.f) ? al1 : NEG_SLOPE * al1;
    float2 ex = make_float2(__expf(al0), __expf(al1));  // no max-shift: |alpha| small
    if (k < N_EDGES)
        exl_csr[epos[k]] = ex;
    else
        exl_self[k - N_EDGES] = ex;
}

// one wave per dst node; lane = channel; shfl-broadcast edge data; 3-deep gather pipeline
__global__ void aggregate_kernel(const int* __restrict__ csr_off, const int* __restrict__ csr_src,
                                 const float2* __restrict__ exl_csr,
                                 const float2* __restrict__ exl_self,
                                 const __half* __restrict__ H16, const float* __restrict__ bias,
                                 float* __restrict__ outp, int do_relu) {
    int wid = (blockIdx.x * blockDim.x + threadIdx.x) >> 6;
    int lane = threadIdx.x & 63;
    if (wid >= N_NODES) return;
    int n = wid;
    float2 exs = exl_self[n];
    float den0 = exs.x, den1 = exs.y;
    float acc0 = exs.x * __half2float(H16[(size_t)n * 128 + lane]);
    float acc1 = exs.y * __half2float(H16[(size_t)n * 128 + 64 + lane]);
    int b = csr_off[n], e = csr_off[n + 1];
    for (int base = b; base < e; base += 64) {
        int j = base + lane;
        int sv = 0;
        float2 exv = make_float2(0.f, 0.f);
        if (j < e) { sv = csr_src[j]; exv = exl_csr[j]; }
        int m = e - base;
        if (m > 64) m = 64;
        // 3-deep rotating prefetch (raw half regs; convert at consume)
        int s;
        __half p0a, p0b, p1a, p1b, p2a, p2b;
        s = __shfl(sv, 0);
        p0a = H16[(size_t)s * 128 + lane]; p0b = H16[(size_t)s * 128 + 64 + lane];
        s = __shfl(sv, 1);
        p1a = H16[(size_t)s * 128 + lane]; p1b = H16[(size_t)s * 128 + 64 + lane];
        s = __shfl(sv, 2);
        p2a = H16[(size_t)s * 128 + lane]; p2b = H16[(size_t)s * 128 + 64 + lane];
        for (int t = 0; t < m; ++t) {
            float ex0 = __shfl(exv.x, t);
            float ex1 = __shfl(exv.y, t);
            float g0 = __half2float(p0a);
            float g1 = __half2float(p0b);
            p0a = p1a; p0b = p1b;
            p1a = p2a; p1b = p2b;
            s = __shfl(sv, (t + 3) & 63);
            p2a = H16[(size_t)s * 128 + lane];
            p2b = H16[(size_t)s * 128 + 64 + lane];
            den0 += ex0; den1 += ex1;
            acc0 = fmaf(ex0, g0, acc0);
            acc1 = fmaf(ex1, g1, acc1);
        }
    }
    float r = 0.5f * (acc0 / (den0 + 1e-16f) + acc1 / (den1 + 1e-16f)) + bias[lane];
    if (do_relu) r = fmaxf(r, 0.f);
    outp[(size_t)n * 64 + lane] = r;
}

// ============================ launch ============================
extern "C" void kernel_launch(void* const* d_in, const int* in_sizes, int n_in,
                              void* d_out, int out_size, void* d_ws, size_t ws_size,
                              hipStream_t stream) {
    const float* x = (const float*)d_in[0];
    const int* ei = (const int*)d_in[1];
    const float* edge_attr = (const float*)d_in[2];
    const float* W1 = (const float*)d_in[3];
    const float* We1 = (const float*)d_in[4];
    const float* as1 = (const float*)d_in[5];
    const float* ad1 = (const float*)d_in[6];
    const float* ae1 = (const float*)d_in[7];
    const float* b1 = (const float*)d_in[8];
    const float* W2 = (const float*)d_in[9];
    const float* We2 = (const float*)d_in[10];
    const float* as2 = (const float*)d_in[11];
    const float* ad2 = (const float*)d_in[12];
    const float* ae2 = (const float*)d_in[13];
    const float* b2 = (const float*)d_in[14];
    float* out = (float*)d_out;

    char* ws = (char*)d_ws;
    size_t off = 0;
    auto alloc = [&](size_t bytes) -> void* {
        void* p = ws + off;
        off += (bytes + 255) & ~(size_t)255;
        return p;
    };
    int* cnt = (int*)alloc((size_t)N_NODES * 4);
    int* cursor = (int*)alloc((size_t)N_NODES * 4);
    int* csr_off = (int*)alloc(((size_t)N_NODES + 1) * 4);
    int* csr_eid = (int*)alloc((size_t)N_EDGES * 4);
    int* csr_src = (int*)alloc((size_t)N_EDGES * 4);
    int* epos = (int*)alloc((size_t)N_EDGES * 4);
    int* bsums = (int*)alloc(256 * 4);
    int* bsums2 = (int*)alloc(256 * 4);
    float* hbuf = (float*)alloc((size_t)N_NODES * 128 * 4);
    __half* H16 = (__half*)alloc((size_t)N_NODES * 128 * 2);
    float* h1 = (float*)alloc((size_t)N_NODES * 64 * 4);
    float* a_src = (float*)alloc((size_t)N_NODES * 2 * 4);
    float* a_dst = (float*)alloc((size_t)N_NODES * 2 * 4);
    float2* exl_csr = (float2*)alloc((size_t)N_EDGES * 8);
    float2* exl_self = (float2*)alloc((size_t)N_NODES * 8);
    float4* a_e4 = (float4*)alloc((size_t)N_EDGES * 16);
    float4* ae_self4 = (float4*)alloc((size_t)N_NODES * 16);
    float* w_e1 = (float*)alloc(32 * 4);
    float* w_e2 = (float*)alloc(32 * 4);

    const int nb = (N_NODES + 255) / 256;

    // ---- CSR + shared edge precompute ----
    hipMemsetAsync(cnt, 0, (size_t)N_NODES * 4, stream);
    count_kernel<<<(N_EDGES + 255) / 256, 256, 0, stream>>>(ei, cnt);
    scan_block_kernel<<<nb, 256, 0, stream>>>(cnt, cursor, bsums, N_NODES);
    scan_block_kernel<<<1, 256, 0, stream>>>(bsums, bsums2, nullptr, nb);
    scan_add_kernel<<<nb, 256, 0, stream>>>(cursor, bsums2, csr_off, cursor, N_NODES, N_EDGES);
    scatter_kernel<<<(N_EDGES + 255) / 256, 256, 0, stream>>>(ei, cursor, csr_eid, csr_src, epos);
    we_kernel<<<1, 64, 0, stream>>>(We1, ae1, w_e1);
    we_kernel<<<1, 64, 0, stream>>>(We2, ae2, w_e2);
    edge_dot_kernel<<<(N_EDGES + 255) / 256, 256, 0, stream>>>(edge_attr, w_e1, w_e2, a_e4);
    self_mean_kernel<<<(N_NODES + 255) / 256, 256, 0, stream>>>(a_e4, csr_off, csr_eid, ae_self4);

    const int nodeWaveBlocks = (N_NODES * 64 + 255) / 256;
    const int edgeBlocks = (N_EDGES + N_NODES + 255) / 256;
    const int gemmBlocks = (N_NODES + 127) / 128;

    // ---- layer 1: IN=128 -> HID=64, H=2, relu ----
    sgemm_kernel<<<gemmBlocks, 256, 0, stream>>>(x, W1, hbuf, H16, N_NODES, 128);
    attdot_kernel<<<nodeWaveBlocks, 256, 0, stream>>>(hbuf, as1, ad1, a_src, a_dst);
    edge_logit_kernel<<<edgeBlocks, 256, 0, stream>>>(ei, (const float2*)a_e4, (const float2*)ae_self4, 0,
                                                      (const float2*)a_src, (const float2*)a_dst,
                                                      epos, exl_csr, exl_self);
    aggregate_kernel<<<nodeWaveBlocks, 256, 0, stream>>>(csr_off, csr_src, exl_csr, exl_self, H16, b1, h1, 1);

    // ---- layer 2: HID=64 -> OUT=64, H=2, no relu ----
    sgemm_kernel<<<gemmBlocks, 256, 0, stream>>>(h1, W2, hbuf, H16, N_NODES, 64);
    attdot_kernel<<<nodeWaveBlocks, 256, 0, stream>>>(hbuf, as2, ad2, a_src, a_dst);
    edge_logit_kernel<<<edgeBlocks, 256, 0, stream>>>(ei, (const float2*)a_e4, (const float2*)ae_self4, 1,
                                                      (const float2*)a_src, (const float2*)a_dst,
                                                      epos, exl_csr, exl_self);
    aggregate_kernel<<<nodeWaveBlocks, 256, 0, stream>>>(csr_off, csr_src, exl_csr, exl_self, H16, b2, out, 0);
}

// Round 5
// 381.063 us; speedup vs baseline: 1.0173x; 1.0063x over previous
//
#include <hip/hip_runtime.h>
#include <hip/hip_fp16.h>

#define N_NODES 50000
#define N_EDGES 800000
#define EDIM 16
#define NEG_SLOPE 0.2f

// ============================ CSR build ============================
__global__ void count_kernel(const int* __restrict__ ei, int* __restrict__ cnt) {
    int e = blockIdx.x * blockDim.x + threadIdx.x;
    if (e < N_EDGES) atomicAdd(&cnt[ei[N_EDGES + e]], 1);
}

__global__ void scan_block_kernel(const int* __restrict__ in, int* __restrict__ excl,
                                  int* __restrict__ bsums, int n) {
    __shared__ int sh[256];
    int tid = threadIdx.x;
    int gid = blockIdx.x * 256 + tid;
    int v = (gid < n) ? in[gid] : 0;
    sh[tid] = v;
    __syncthreads();
    for (int off = 1; off < 256; off <<= 1) {
        int t = (tid >= off) ? sh[tid - off] : 0;
        __syncthreads();
        sh[tid] += t;
        __syncthreads();
    }
    if (gid < n) excl[gid] = sh[tid] - v;
    if (bsums != nullptr && tid == 255) bsums[blockIdx.x] = sh[tid];
}

__global__ void scan_add_kernel(const int* __restrict__ excl, const int* __restrict__ bs2,
                                int* __restrict__ csr_off, int* __restrict__ cursor,
                                int n, int total) {
    int gid = blockIdx.x * 256 + threadIdx.x;
    if (gid < n) {
        int v = excl[gid] + bs2[gid >> 8];
        csr_off[gid] = v;
        cursor[gid] = v;
    }
    if (gid == 0) csr_off[n] = total;
}

// writes CSR edge id, CSR src node, and edge->CSR-slot map
__global__ void scatter_kernel(const int* __restrict__ ei, int* __restrict__ cursor,
                               int* __restrict__ csr_eid, int* __restrict__ csr_src,
                               int* __restrict__ epos) {
    int e = blockIdx.x * blockDim.x + threadIdx.x;
    if (e < N_EDGES) {
        int s = ei[e];
        int d = ei[N_EDGES + e];
        int pos = atomicAdd(&cursor[d], 1);
        csr_eid[pos] = e;
        csr_src[pos] = s;
        epos[e] = pos;
    }
}

// ============================ shared precompute ============================
// w_e[h*16+d] = sum_c We[d][h*64+c] * ae[h][c]
__global__ void we_kernel(const float* __restrict__ We, const float* __restrict__ ae,
                          float* __restrict__ w_e) {
    int idx = threadIdx.x;
    if (idx >= 32) return;
    int h = idx >> 4, d = idx & 15;
    float s = 0.f;
    for (int c = 0; c < 64; ++c) s += We[d * 128 + h * 64 + c] * ae[h * 64 + c];
    w_e[idx] = s;
}

// per-edge attention-edge dots for BOTH layers: a_e4[k] = {l1h0, l1h1, l2h0, l2h1}
__global__ void edge_dot_kernel(const float* __restrict__ edge_attr,
                                const float* __restrict__ we1, const float* __restrict__ we2,
                                float4* __restrict__ a_e4) {
    int k = blockIdx.x * blockDim.x + threadIdx.x;
    if (k >= N_EDGES) return;
    float4 d = make_float4(0.f, 0.f, 0.f, 0.f);
#pragma unroll
    for (int q = 0; q < 4; ++q) {
        float4 v = *reinterpret_cast<const float4*>(edge_attr + (size_t)k * 16 + q * 4);
        float4 wa = *reinterpret_cast<const float4*>(we1 + q * 4);
        float4 wb = *reinterpret_cast<const float4*>(we1 + 16 + q * 4);
        float4 wc = *reinterpret_cast<const float4*>(we2 + q * 4);
        float4 wd = *reinterpret_cast<const float4*>(we2 + 16 + q * 4);
        d.x += v.x * wa.x + v.y * wa.y + v.z * wa.z + v.w * wa.w;
        d.y += v.x * wb.x + v.y * wb.y + v.z * wb.z + v.w * wb.w;
        d.z += v.x * wc.x + v.y * wc.y + v.z * wc.z + v.w * wc.w;
        d.w += v.x * wd.x + v.y * wd.y + v.z * wd.z + v.w * wd.w;
    }
    a_e4[k] = d;
}

// self-loop edge dot = mean of incoming edges' dots (linearity of dot vs mean attr)
__global__ void self_mean_kernel(const float4* __restrict__ a_e4, const int* __restrict__ csr_off,
                                 const int* __restrict__ csr_eid, float4* __restrict__ ae_self) {
    int n = blockIdx.x * blockDim.x + threadIdx.x;
    if (n >= N_NODES) return;
    int b = csr_off[n], e = csr_off[n + 1];
    float4 s = make_float4(0.f, 0.f, 0.f, 0.f);
    for (int j = b; j < e; ++j) {
        float4 v = a_e4[csr_eid[j]];
        s.x += v.x; s.y += v.y; s.z += v.z; s.w += v.w;
    }
    float inv = 1.f / (float)((e - b) > 0 ? (e - b) : 1);
    s.x *= inv; s.y *= inv; s.z *= inv; s.w *= inv;
    ae_self[n] = s;
}

// ============================ per-layer ============================
// C[M,128] = X[M,K] @ W[K,128]; also writes fp16 copy for the gather kernel
__global__ __launch_bounds__(256) void sgemm_kernel(const float* __restrict__ X,
                                                    const float* __restrict__ W,
                                                    float* __restrict__ Hout,
                                                    __half* __restrict__ H16, int M, int K) {
    __shared__ float xs[128 * 132];
    __shared__ float ws[128 * 132];
    const int tid = threadIdx.x;
    const int row0 = blockIdx.x * 128;
    const int xstride = K + 4;

    for (int q = tid; q < K * 32; q += 256) {
        int k = q >> 5, c4 = q & 31;
        float4 v = *reinterpret_cast<const float4*>(W + k * 128 + c4 * 4);
        *reinterpret_cast<float4*>(&ws[k * 132 + c4 * 4]) = v;
    }
    const int kshift = (K == 128) ? 5 : 4;
    const int kmask = (K >> 2) - 1;
    for (int q = tid; q < (128 << kshift); q += 256) {
        int r = q >> kshift, kq = q & kmask;
        int gr = row0 + r;
        float4 v = make_float4(0.f, 0.f, 0.f, 0.f);
        if (gr < M) v = *reinterpret_cast<const float4*>(X + (size_t)gr * K + kq * 4);
        *reinterpret_cast<float4*>(&xs[r * xstride + kq * 4]) = v;
    }
    __syncthreads();

    const int cg = tid & 15;
    const int rg = (tid >> 4) & 3;
    const int w = tid >> 6;
    const int rbase = w * 32 + rg;

    float acc[8][8];
#pragma unroll
    for (int i = 0; i < 8; ++i)
#pragma unroll
        for (int j = 0; j < 8; ++j) acc[i][j] = 0.f;

    for (int kk = 0; kk < K; kk += 4) {
        float4 a[8], b[8];
#pragma unroll
        for (int i = 0; i < 8; ++i)
            a[i] = *reinterpret_cast<const float4*>(&xs[(rbase + 4 * i) * xstride + kk]);
#pragma unroll
        for (int t = 0; t < 4; ++t) {
            b[t * 2] = *reinterpret_cast<const float4*>(&ws[(kk + t) * 132 + cg * 8]);
            b[t * 2 + 1] = *reinterpret_cast<const float4*>(&ws[(kk + t) * 132 + cg * 8 + 4]);
        }
#pragma unroll
        for (int t = 0; t < 4; ++t) {
            float bv[8];
            bv[0] = b[t * 2].x; bv[1] = b[t * 2].y; bv[2] = b[t * 2].z; bv[3] = b[t * 2].w;
            bv[4] = b[t * 2 + 1].x; bv[5] = b[t * 2 + 1].y; bv[6] = b[t * 2 + 1].z; bv[7] = b[t * 2 + 1].w;
#pragma unroll
            for (int i = 0; i < 8; ++i) {
                float av = (t == 0) ? a[i].x : (t == 1) ? a[i].y : (t == 2) ? a[i].z : a[i].w;
#pragma unroll
                for (int j = 0; j < 8; ++j) acc[i][j] = fmaf(av, bv[j], acc[i][j]);
            }
        }
    }
#pragma unroll
    for (int i = 0; i < 8; ++i) {
        int r = row0 + rbase + 4 * i;
        if (r < M) {
            float4 o0 = {acc[i][0], acc[i][1], acc[i][2], acc[i][3]};
            float4 o1 = {acc[i][4], acc[i][5], acc[i][6], acc[i][7]};
            *reinterpret_cast<float4*>(Hout + (size_t)r * 128 + cg * 8) = o0;
            *reinterpret_cast<float4*>(Hout + (size_t)r * 128 + cg * 8 + 4) = o1;
            __half t16[8];
#pragma unroll
            for (int j = 0; j < 8; ++j) t16[j] = __float2half_rn(acc[i][j]);
            *reinterpret_cast<float4*>(H16 + (size_t)r * 128 + cg * 8) =
                *reinterpret_cast<const float4*>(t16);
        }
    }
}

// a_src[n][h], a_dst[n][h]; one wave per node
__global__ void attdot_kernel(const float* __restrict__ Hb, const float* __restrict__ as,
                              const float* __restrict__ ad, float* __restrict__ a_src,
                              float* __restrict__ a_dst) {
    int wid = (blockIdx.x * blockDim.x + threadIdx.x) >> 6;
    int lane = threadIdx.x & 63;
    if (wid >= N_NODES) return;
    float h0 = Hb[(size_t)wid * 128 + lane];
    float h1 = Hb[(size_t)wid * 128 + 64 + lane];
    float s0 = h0 * as[lane], s1 = h1 * as[64 + lane];
    float d0 = h0 * ad[lane], d1 = h1 * ad[64 + lane];
#pragma unroll
    for (int m = 32; m; m >>= 1) {
        s0 += __shfl_xor(s0, m);
        s1 += __shfl_xor(s1, m);
        d0 += __shfl_xor(d0, m);
        d1 += __shfl_xor(d1, m);
    }
    if (lane == 0) {
        *reinterpret_cast<float2*>(a_src + wid * 2) = make_float2(s0, s1);
        *reinterpret_cast<float2*>(a_dst + wid * 2) = make_float2(d0, d1);
    }
}

// exp(leaky_relu(logit)); edges write into CSR order, self-loops into exl_self
__global__ void edge_logit_kernel(const int* __restrict__ ei,
                                  const float2* __restrict__ ae_pairs,      // a_e4 as float2[2E]
                                  const float2* __restrict__ ae_self_pairs, // ae_self as float2[2N]
                                  int layer,
                                  const float2* __restrict__ a_src, const float2* __restrict__ a_dst,
                                  const int* __restrict__ epos,
                                  float2* __restrict__ exl_csr, float2* __restrict__ exl_self) {
    int k = blockIdx.x * blockDim.x + threadIdx.x;
    if (k >= N_EDGES + N_NODES) return;
    float2 ae, asv, adv;
    if (k < N_EDGES) {
        int s = ei[k], d = ei[N_EDGES + k];
        ae = ae_pairs[2 * (size_t)k + layer];
        asv = a_src[s];
        adv = a_dst[d];
    } else {
        int n = k - N_EDGES;
        ae = ae_self_pairs[2 * (size_t)n + layer];
        asv = a_src[n];
        adv = a_dst[n];
    }
    float al0 = asv.x + adv.x + ae.x;
    float al1 = asv.y + adv.y + ae.y;
    al0 = (al0 > 0.f) ? al0 : NEG_SLOPE * al0;
    al1 = (al1 > 0.f) ? al1 : NEG_SLOPE * al1;
    float2 ex = make_float2(__expf(al0), __expf(al1));  // no max-shift: |alpha| small
    if (k < N_EDGES)
        exl_csr[epos[k]] = ex;
    else
        exl_self[k - N_EDGES] = ex;
}

// one wave per dst node; lane = channel; shfl-broadcast edge data; 3-deep gather pipeline
__global__ void aggregate_kernel(const int* __restrict__ csr_off, const int* __restrict__ csr_src,
                                 const float2* __restrict__ exl_csr,
                                 const float2* __restrict__ exl_self,
                                 const __half* __restrict__ H16, const float* __restrict__ bias,
                                 float* __restrict__ outp, int do_relu) {
    int wid = (blockIdx.x * blockDim.x + threadIdx.x) >> 6;
    int lane = threadIdx.x & 63;
    if (wid >= N_NODES) return;
    int n = wid;
    float2 exs = exl_self[n];
    float den0 = exs.x, den1 = exs.y;
    float acc0 = exs.x * __half2float(H16[(size_t)n * 128 + lane]);
    float acc1 = exs.y * __half2float(H16[(size_t)n * 128 + 64 + lane]);
    int b = csr_off[n], e = csr_off[n + 1];
    for (int base = b; base < e; base += 64) {
        int j = base + lane;
        int sv = 0;
        float2 exv = make_float2(0.f, 0.f);
        if (j < e) { sv = csr_src[j]; exv = exl_csr[j]; }
        int m = e - base;
        if (m > 64) m = 64;
        // 3-deep rotating prefetch (raw half regs; convert at consume)
        int s;
        __half p0a, p0b, p1a, p1b, p2a, p2b;
        s = __shfl(sv, 0);
        p0a = H16[(size_t)s * 128 + lane]; p0b = H16[(size_t)s * 128 + 64 + lane];
        s = __shfl(sv, 1);
        p1a = H16[(size_t)s * 128 + lane]; p1b = H16[(size_t)s * 128 + 64 + lane];
        s = __shfl(sv, 2);
        p2a = H16[(size_t)s * 128 + lane]; p2b = H16[(size_t)s * 128 + 64 + lane];
        for (int t = 0; t < m; ++t) {
            float ex0 = __shfl(exv.x, t);
            float ex1 = __shfl(exv.y, t);
            float g0 = __half2float(p0a);
            float g1 = __half2float(p0b);
            p0a = p1a; p0b = p1b;
            p1a = p2a; p1b = p2b;
            s = __shfl(sv, (t + 3) & 63);
            p2a = H16[(size_t)s * 128 + lane];
            p2b = H16[(size_t)s * 128 + 64 + lane];
            den0 += ex0; den1 += ex1;
            acc0 = fmaf(ex0, g0, acc0);
            acc1 = fmaf(ex1, g1, acc1);
        }
    }
    float r = 0.5f * (acc0 / (den0 + 1e-16f) + acc1 / (den1 + 1e-16f)) + bias[lane];
    if (do_relu) r = fmaxf(r, 0.f);
    outp[(size_t)n * 64 + lane] = r;
}

// ============================ launch ============================
extern "C" void kernel_launch(void* const* d_in, const int* in_sizes, int n_in,
                              void* d_out, int out_size, void* d_ws, size_t ws_size,
                              hipStream_t stream) {
    const float* x = (const float*)d_in[0];
    const int* ei = (const int*)d_in[1];
    const float* edge_attr = (const float*)d_in[2];
    const float* W1 = (const float*)d_in[3];
    const float* We1 = (const float*)d_in[4];
    const float* as1 = (const float*)d_in[5];
    const float* ad1 = (const float*)d_in[6];
    const float* ae1 = (const float*)d_in[7];
    const float* b1 = (const float*)d_in[8];
    const float* W2 = (const float*)d_in[9];
    const float* We2 = (const float*)d_in[10];
    const float* as2 = (const float*)d_in[11];
    const float* ad2 = (const float*)d_in[12];
    const float* ae2 = (const float*)d_in[13];
    const float* b2 = (const float*)d_in[14];
    float* out = (float*)d_out;

    char* ws = (char*)d_ws;
    size_t off = 0;
    auto alloc = [&](size_t bytes) -> void* {
        void* p = ws + off;
        off += (bytes + 255) & ~(size_t)255;
        return p;
    };
    int* cnt = (int*)alloc((size_t)N_NODES * 4);
    int* cursor = (int*)alloc((size_t)N_NODES * 4);
    int* csr_off = (int*)alloc(((size_t)N_NODES + 1) * 4);
    int* csr_eid = (int*)alloc((size_t)N_EDGES * 4);
    int* csr_src = (int*)alloc((size_t)N_EDGES * 4);
    int* epos = (int*)alloc((size_t)N_EDGES * 4);
    int* bsums = (int*)alloc(256 * 4);
    int* bsums2 = (int*)alloc(256 * 4);
    float* hbuf = (float*)alloc((size_t)N_NODES * 128 * 4);
    __half* H16 = (__half*)alloc((size_t)N_NODES * 128 * 2);
    float* h1 = (float*)alloc((size_t)N_NODES * 64 * 4);
    float* a_src = (float*)alloc((size_t)N_NODES * 2 * 4);
    float* a_dst = (float*)alloc((size_t)N_NODES * 2 * 4);
    float2* exl_csr = (float2*)alloc((size_t)N_EDGES * 8);
    float2* exl_self = (float2*)alloc((size_t)N_NODES * 8);
    float4* a_e4 = (float4*)alloc((size_t)N_EDGES * 16);
    float4* ae_self4 = (float4*)alloc((size_t)N_NODES * 16);
    float* w_e1 = (float*)alloc(32 * 4);
    float* w_e2 = (float*)alloc(32 * 4);

    const int nb = (N_NODES + 255) / 256;

    // ---- CSR + shared edge precompute ----
    hipMemsetAsync(cnt, 0, (size_t)N_NODES * 4, stream);
    count_kernel<<<(N_EDGES + 255) / 256, 256, 0, stream>>>(ei, cnt);
    scan_block_kernel<<<nb, 256, 0, stream>>>(cnt, cursor, bsums, N_NODES);
    scan_block_kernel<<<1, 256, 0, stream>>>(bsums, bsums2, nullptr, nb);
    scan_add_kernel<<<nb, 256, 0, stream>>>(cursor, bsums2, csr_off, cursor, N_NODES, N_EDGES);
    scatter_kernel<<<(N_EDGES + 255) / 256, 256, 0, stream>>>(ei, cursor, csr_eid, csr_src, epos);
    we_kernel<<<1, 64, 0, stream>>>(We1, ae1, w_e1);
    we_kernel<<<1, 64, 0, stream>>>(We2, ae2, w_e2);
    edge_dot_kernel<<<(N_EDGES + 255) / 256, 256, 0, stream>>>(edge_attr, w_e1, w_e2, a_e4);
    self_mean_kernel<<<(N_NODES + 255) / 256, 256, 0, stream>>>(a_e4, csr_off, csr_eid, ae_self4);

    const int nodeWaveBlocks = (N_NODES * 64 + 255) / 256;
    const int edgeBlocks = (N_EDGES + N_NODES + 255) / 256;
    const int gemmBlocks = (N_NODES + 127) / 128;

    // ---- layer 1: IN=128 -> HID=64, H=2, relu ----
    sgemm_kernel<<<gemmBlocks, 256, 0, stream>>>(x, W1, hbuf, H16, N_NODES, 128);
    attdot_kernel<<<nodeWaveBlocks, 256, 0, stream>>>(hbuf, as1, ad1, a_src, a_dst);
    edge_logit_kernel<<<edgeBlocks, 256, 0, stream>>>(ei, (const float2*)a_e4, (const float2*)ae_self4, 0,
                                                      (const float2*)a_src, (const float2*)a_dst,
                                                      epos, exl_csr, exl_self);
    aggregate_kernel<<<nodeWaveBlocks, 256, 0, stream>>>(csr_off, csr_src, exl_csr, exl_self, H16, b1, h1, 1);

    // ---- layer 2: HID=64 -> OUT=64, H=2, no relu ----
    sgemm_kernel<<<gemmBlocks, 256, 0, stream>>>(h1, W2, hbuf, H16, N_NODES, 64);
    attdot_kernel<<<nodeWaveBlocks, 256, 0, stream>>>(hbuf, as2, ad2, a_src, a_dst);
    edge_logit_kernel<<<edgeBlocks, 256, 0, stream>>>(ei, (const float2*)a_e4, (const float2*)ae_self4, 1,
                                                      (const float2*)a_src, (const float2*)a_dst,
                                                      epos, exl_csr, exl_self);
    aggregate_kernel<<<nodeWaveBlocks, 256, 0, stream>>>(csr_off, csr_src, exl_csr, exl_self, H16, b2, out, 0);
}